// Round 3
// baseline (693.220 us; speedup 1.0000x reference)
//
#include <hip/hip_runtime.h>
#include <math.h>

typedef unsigned long long u64;
typedef unsigned int u32;

#define N_ROWS 8192
#define DIM 1024
#define KCLS 80
#define KC1 81
#define MCAND 2048
#define TOPK_ 100
#define CMAX 163840
#define SURV_MAX 32768
#define NSPLIT 4
#define NBINS 8192
#define BIN_BASE 125440
#define SCORE_T 0.05
#define NMS_T 0.5f
#define MAX_COORD_F 1217.0f
#define SCALE_CLAMP_F 4.135166556742356f
#define IMG_W_F 1216.0f
#define IMG_H_F 800.0f

__device__ __forceinline__ int score_bin(double p) {
  u32 bits = __float_as_uint((float)p);
  int b = (int)(bits >> 13) - BIN_BASE;
  return b < 0 ? 0 : (b > NBINS - 1 ? NBINS - 1 : b);
}

__device__ __forceinline__ u64 readlane64(u64 v, int l) {
  u32 lo = __builtin_amdgcn_readlane((u32)v, l);
  u32 hi = __builtin_amdgcn_readlane((u32)(v >> 32), l);
  return ((u64)hi << 32) | (u64)lo;
}

// ---------------------------------------------------------------- init
__global__ void k_init(int* counter, int* scount, int* tbin, int* hist,
                       int* cnt, double* selS, u32* selI) {
  int t = blockIdx.x * blockDim.x + threadIdx.x;
  if (t == 0) { *counter = 0; *scount = 0; *tbin = 0; }
  if (t < NBINS) hist[t] = 0;
  if (t < SURV_MAX) cnt[t] = 0;
  if (t < MCAND) { selS[t] = -1.0; selI[t] = 0u; }  // sentinel (score=-1 -> invalid)
}

// ------------------------------------- cls GEMM (f64 acc) + softmax + compact
#define BK 32
#define XT_STRIDE 34
#define BT_STRIDE 96

__global__ __launch_bounds__(256) void k_gemm_softmax(
    const float* __restrict__ x, const float* __restrict__ w,
    const float* __restrict__ bias, double* __restrict__ scd,
    u32* __restrict__ cid, int* __restrict__ counter)
{
  __shared__ float xt[BK][XT_STRIDE];
  __shared__ float bt[BK][BT_STRIDE];
  __shared__ double red[16][32];
  __shared__ double rowM[32];
  __shared__ double rowS[32];

  const int tid = threadIdx.x;
  const int rb = blockIdx.x * 32;
  const int cx = tid >> 4;   // 0..15
  const int ry = tid & 15;   // 0..15

  double acc[2][6];
#pragma unroll
  for (int i = 0; i < 2; i++)
#pragma unroll
    for (int j = 0; j < 6; j++) acc[i][j] = 0.0;

  const int sr  = tid >> 3;        // 0..31 stage row
  const int skq = (tid & 7) * 4;   // 0,4,...,28

  for (int k0 = 0; k0 < DIM; k0 += BK) {
    float4 xv4 = *(const float4*)(x + (size_t)(rb + sr) * DIM + k0 + skq);
    float breg[12];
#pragma unroll
    for (int q = 0; q < 12; ++q) {
      int e = tid + q * 256;        // 0..3071 over 32x96
      int k = e / 96, c = e - k * 96;
      breg[q] = (c < KC1) ? w[(size_t)(k0 + k) * KC1 + c] : 0.0f;
    }
    __syncthreads();
    xt[skq + 0][sr] = xv4.x; xt[skq + 1][sr] = xv4.y;
    xt[skq + 2][sr] = xv4.z; xt[skq + 3][sr] = xv4.w;
#pragma unroll
    for (int q = 0; q < 12; ++q) ((float*)bt)[tid + q * 256] = breg[q];
    __syncthreads();

#pragma unroll
    for (int k = 0; k < BK; ++k) {
      float2 xv = *(const float2*)&xt[k][ry * 2];
      float2 b0 = *(const float2*)&bt[k][cx * 6];
      float2 b1 = *(const float2*)&bt[k][cx * 6 + 2];
      float2 b2 = *(const float2*)&bt[k][cx * 6 + 4];
      double xd0 = (double)xv.x, xd1 = (double)xv.y;
      double bd[6] = {(double)b0.x, (double)b0.y, (double)b1.x,
                      (double)b1.y, (double)b2.x, (double)b2.y};
#pragma unroll
      for (int j = 0; j < 6; j++) {
        acc[0][j] = fma(xd0, bd[j], acc[0][j]);
        acc[1][j] = fma(xd1, bd[j], acc[1][j]);
      }
    }
    __syncthreads();
  }

  double bb[6];
#pragma unroll
  for (int j = 0; j < 6; j++) {
    int c = cx * 6 + j;
    bb[j] = (c < KC1) ? (double)bias[c] : 0.0;
  }
  double pm[2] = {-1e300, -1e300};
#pragma unroll
  for (int i = 0; i < 2; i++)
#pragma unroll
    for (int j = 0; j < 6; j++) {
      int c = cx * 6 + j;
      if (c < KC1) pm[i] = fmax(pm[i], acc[i][j] + bb[j]);
    }
  red[cx][ry * 2 + 0] = pm[0];
  red[cx][ry * 2 + 1] = pm[1];
  __syncthreads();
  if (tid < 32) {
    double m = -1e300;
#pragma unroll
    for (int q = 0; q < 16; q++) m = fmax(m, red[q][tid]);
    rowM[tid] = m;
  }
  __syncthreads();
  double ps[2] = {0.0, 0.0};
#pragma unroll
  for (int i = 0; i < 2; i++) {
    double m = rowM[ry * 2 + i];
#pragma unroll
    for (int j = 0; j < 6; j++) {
      int c = cx * 6 + j;
      if (c < KC1) ps[i] += exp(acc[i][j] + bb[j] - m);
    }
  }
  __syncthreads();
  red[cx][ry * 2 + 0] = ps[0];
  red[cx][ry * 2 + 1] = ps[1];
  __syncthreads();
  if (tid < 32) {
    double s = 0.0;
#pragma unroll
    for (int q = 0; q < 16; q++) s += red[q][tid];
    rowS[tid] = s;
  }
  __syncthreads();
#pragma unroll
  for (int i = 0; i < 2; i++) {
    int rloc = ry * 2 + i;
    double m = rowM[rloc], s = rowS[rloc];
#pragma unroll
    for (int j = 0; j < 6; j++) {
      int c = cx * 6 + j;
      if (c < KCLS) {
        double p = exp(acc[i][j] + bb[j] - m) / s;
        if (p > SCORE_T) {
          int pos = atomicAdd(counter, 1);
          if (pos < CMAX) {
            scd[pos] = p;
            cid[pos] = (u32)((rb + rloc) * KCLS + c);
          }
        }
      }
    }
  }
}

// -------------------------------------------- histogram of float-key bins
__global__ __launch_bounds__(256) void k_hist(
    const double* __restrict__ sc, const int* __restrict__ counter,
    int* __restrict__ hist)
{
  int C = *counter; if (C > CMAX) C = CMAX;
  for (int e = blockIdx.x * 256 + threadIdx.x; e < C; e += gridDim.x * 256)
    atomicAdd(&hist[score_bin(sc[e])], 1);
}

// -------------------------------------- find threshold bin (suffix >= MCAND)
__global__ __launch_bounds__(256) void k_thresh(
    const int* __restrict__ hist, int* __restrict__ tbin)
{
  __shared__ int h[NBINS];
  __shared__ int segsum[256];
  __shared__ int segsuf[256];
  const int tid = threadIdx.x;
  for (int e = tid; e < NBINS; e += 256) h[e] = hist[e];
  __syncthreads();
  int s = 0;
#pragma unroll
  for (int q = 0; q < NBINS / 256; ++q) s += h[tid * (NBINS / 256) + q];
  segsum[tid] = s;
  __syncthreads();
  if (tid == 0) {
    int run = 0;
    for (int t = 255; t >= 0; --t) { segsuf[t] = run; run += segsum[t]; }
  }
  __syncthreads();
  int run = segsuf[tid];
  if (run < MCAND) {
    const int lo = tid * (NBINS / 256);
    for (int b = lo + NBINS / 256 - 1; b >= lo; --b) {
      run += h[b];
      if (run >= MCAND) { *tbin = b; break; }
    }
  }
}

// ------------------------------------------------- compact survivors (bin>=T)
__global__ __launch_bounds__(256) void k_compact(
    const double* __restrict__ sc, const u32* __restrict__ id,
    const int* __restrict__ counter, const int* __restrict__ tbin,
    double* __restrict__ ssc, u32* __restrict__ sid, int* __restrict__ scount)
{
  int C = *counter; if (C > CMAX) C = CMAX;
  const int T = *tbin;
  for (int e = blockIdx.x * 256 + threadIdx.x; e < C; e += gridDim.x * 256) {
    double p = sc[e];
    if (score_bin(p) >= T) {
      int pos = atomicAdd(scount, 1);
      if (pos < SURV_MAX) { ssc[pos] = p; sid[pos] = id[e]; }
    }
  }
}

// --------------------------- exact rank-count among survivors (j-range split)
__global__ __launch_bounds__(256) void k_rank(
    const double* __restrict__ ssc, const u32* __restrict__ sid,
    const int* __restrict__ scount, int* __restrict__ cnt)
{
  __shared__ double lsc[2048];
  __shared__ u32 lid[2048];
  int S = *scount; if (S > SURV_MAX) S = SURV_MAX;
  const int i = blockIdx.x * 256 + threadIdx.x;
  if (blockIdx.x * 256 >= S) return;
  const double si = (i < S) ? ssc[i] : -2.0;
  const u32 ii = (i < S) ? sid[i] : 0u;
  const int seg = (S + NSPLIT - 1) / NSPLIT;
  const int jlo = blockIdx.y * seg;
  const int jhi = min(S, jlo + seg);
  int c = 0;
  for (int base = jlo; base < jhi; base += 2048) {
    const int n = min(2048, jhi - base);
    __syncthreads();
    for (int e = threadIdx.x; e < n; e += 256) { lsc[e] = ssc[base + e]; lid[e] = sid[base + e]; }
    __syncthreads();
    if (i < S) {
      for (int j = 0; j < n; ++j) {
        double sj = lsc[j];
        c += (sj > si || (sj == si && lid[j] < ii)) ? 1 : 0;
      }
    }
  }
  if (i < S && c > 0) atomicAdd(&cnt[i], c);
}

// ----------------------------------------------------- scatter by final rank
__global__ __launch_bounds__(256) void k_scatter(
    const double* __restrict__ ssc, const u32* __restrict__ sid,
    const int* __restrict__ scount, const int* __restrict__ cnt,
    double* __restrict__ selS, u32* __restrict__ selI)
{
  int S = *scount; if (S > SURV_MAX) S = SURV_MAX;
  const int i = blockIdx.x * 256 + threadIdx.x;
  if (i < S) {
    int c = cnt[i];
    if (c < MCAND) { selS[c] = ssc[i]; selI[c] = sid[i]; }
  }
}

// -------------------------------- per-candidate bbox delta dot + decode + clip
__global__ __launch_bounds__(256) void k_gather_decode(
    const double* __restrict__ selS, const u32* __restrict__ selI,
    const float* __restrict__ x, const float* __restrict__ bw,
    const float* __restrict__ bbias, const float* __restrict__ proposals,
    float4* __restrict__ dbox, float4* __restrict__ obox,
    float* __restrict__ areav, float* __restrict__ scorev,
    int* __restrict__ clsv, int* __restrict__ validv)
{
  __shared__ double wred[4][4];
  const int r = blockIdx.x;
  const double s = selS[r];
  const u32 idx = selI[r];
  const int row = (int)(idx / 80u);
  const int cls = (int)(idx - (u32)row * 80u);

  const float* xr = x + (size_t)row * DIM;
  const float4* bwv = (const float4*)bw;  // [DIM][80] of float4
  double a0 = 0, a1 = 0, a2 = 0, a3 = 0;
  for (int k = threadIdx.x; k < DIM; k += 256) {
    double xv = (double)xr[k];
    float4 wv = bwv[(size_t)k * 80 + cls];
    a0 = fma(xv, (double)wv.x, a0);
    a1 = fma(xv, (double)wv.y, a1);
    a2 = fma(xv, (double)wv.z, a2);
    a3 = fma(xv, (double)wv.w, a3);
  }
#pragma unroll
  for (int off = 32; off > 0; off >>= 1) {
    a0 += __shfl_down(a0, off);
    a1 += __shfl_down(a1, off);
    a2 += __shfl_down(a2, off);
    a3 += __shfl_down(a3, off);
  }
  int lane = threadIdx.x & 63, wid = threadIdx.x >> 6;
  if (lane == 0) { wred[wid][0] = a0; wred[wid][1] = a1; wred[wid][2] = a2; wred[wid][3] = a3; }
  __syncthreads();
  if (threadIdx.x == 0) {
    double d0 = wred[0][0] + wred[1][0] + wred[2][0] + wred[3][0] + (double)bbias[cls * 4 + 0];
    double d1 = wred[0][1] + wred[1][1] + wred[2][1] + wred[3][1] + (double)bbias[cls * 4 + 1];
    double d2 = wred[0][2] + wred[1][2] + wred[2][2] + wred[3][2] + (double)bbias[cls * 4 + 2];
    double d3 = wred[0][3] + wred[1][3] + wred[2][3] + wred[3][3] + (double)bbias[cls * 4 + 3];
    float4 p = ((const float4*)proposals)[row];
    float w = p.z - p.x, h = p.w - p.y;
    float cxx = p.x + 0.5f * w, cyy = p.y + 0.5f * h;
    float dx = (float)d0 / 10.0f;
    float dy = (float)d1 / 10.0f;
    float dw = fminf((float)d2 / 5.0f, SCALE_CLAMP_F);
    float dh = fminf((float)d3 / 5.0f, SCALE_CLAMP_F);
    float pcx = dx * w + cxx, pcy = dy * h + cyy;
    float pw = expf(dw) * w, ph = expf(dh) * h;
    float x1 = pcx - 0.5f * pw, y1 = pcy - 0.5f * ph;
    float x2 = pcx + 0.5f * pw, y2 = pcy + 0.5f * ph;
    x1 = fminf(fmaxf(x1, 0.0f), IMG_W_F);
    x2 = fminf(fmaxf(x2, 0.0f), IMG_W_F);
    y1 = fminf(fmaxf(y1, 0.0f), IMG_H_F);
    y2 = fminf(fmaxf(y2, 0.0f), IMG_H_F);
    float4 db = {x1, y1, x2, y2};
    dbox[r] = db;
    float ofs = (float)cls * MAX_COORD_F;
    float4 ob = {x1 + ofs, y1 + ofs, x2 + ofs, y2 + ofs};
    obox[r] = ob;
    areav[r] = (ob.z - ob.x) * (ob.w - ob.y);
    scorev[r] = (float)s;
    clsv[r] = cls;
    validv[r] = (s > SCORE_T) ? 1 : 0;
  }
}

// ------------------------------------------------ pairwise suppression bitmask
__global__ __launch_bounds__(256) void k_nms_mask(
    const float4* __restrict__ obox, const float* __restrict__ areav,
    u64* __restrict__ mask)
{
  __shared__ float4 sb[MCAND];
  __shared__ float sa[MCAND];
  const int i = blockIdx.x;
  for (int e = threadIdx.x; e < MCAND; e += 256) { sb[e] = obox[e]; sa[e] = areav[e]; }
  __syncthreads();
  float4 bi = sb[i];
  float ai = sa[i];
  int lane = threadIdx.x & 63, wid = threadIdx.x >> 6;
#pragma unroll
  for (int it = 0; it < MCAND / 256; ++it) {
    int j = it * 256 + threadIdx.x;
    float4 bj = sb[j];
    float xx1 = fmaxf(bi.x, bj.x);
    float yy1 = fmaxf(bi.y, bj.y);
    float xx2 = fminf(bi.z, bj.z);
    float yy2 = fminf(bi.w, bj.w);
    float inter = fmaxf(xx2 - xx1, 0.0f) * fmaxf(yy2 - yy1, 0.0f);
    float uni = ai + sa[j] - inter;
    float iou = inter / fmaxf(uni, 1e-9f);
    bool pred = (iou > NMS_T) && (j > i);
    u64 b = __ballot(pred);
    if (lane == 0) mask[(size_t)i * 32 + it * 4 + wid] = b;
  }
}

// --------------------- sequential suppression scan (1 wave, chunked scalar)
__global__ __launch_bounds__(64) void k_nms_reduce(
    const u64* __restrict__ mask, const int* __restrict__ validv,
    int* __restrict__ keep)
{
  __shared__ u64 lvalid[32];
  __shared__ u64 lsup[32];
  const int lane = threadIdx.x;  // 0..63, one wave

  // build valid bit-vector: word k = bits for candidates 64k..64k+63
#pragma unroll 4
  for (int k = 0; k < 32; ++k) {
    u64 b = __ballot(validv[k * 64 + lane] != 0);
    if (lane == 0) lvalid[k] = b;
  }
  __syncthreads();
  u64 validw = (lane < 32) ? lvalid[lane] : 0;
  u64 supw = 0;

  // prefetched diagonal word: row (64c+lane), word c
  u64 Mcur = mask[(size_t)lane * 32 + 0];

  for (int c = 0; c < 32; ++c) {
    u64 Mnext = (c < 31) ? mask[((size_t)(c + 1) * 64 + lane) * 32 + (c + 1)] : 0;

    u64 s_sup = readlane64(supw, c);
    u64 s_val = readlane64(validw, c);
    u64 todo = s_val & ~s_sup;
    u64 aliveM = 0;
    while (todo) {
      int b = __builtin_ctzll(todo);
      b = __builtin_amdgcn_readfirstlane(b);
      u64 row = readlane64(Mcur, b);   // intra-chunk suppression from alive b
      s_sup |= row;
      aliveM |= (1ull << b);
      u64 done = (b == 63) ? ~0ull : ((1ull << (b + 1)) - 1);
      todo = s_val & ~s_sup & ~done;
    }

    // apply alive rows of this chunk to the full sup vector (batched x4)
    u64 am = aliveM;
    while (am) {
      u64 r0 = 0, r1 = 0, r2 = 0, r3 = 0;
      int b0 = __builtin_ctzll(am); am &= am - 1;
      if (lane < 32) r0 = mask[((size_t)(c * 64 + b0)) * 32 + lane];
      if (am) {
        int b1 = __builtin_ctzll(am); am &= am - 1;
        if (lane < 32) r1 = mask[((size_t)(c * 64 + b1)) * 32 + lane];
      }
      if (am) {
        int b2 = __builtin_ctzll(am); am &= am - 1;
        if (lane < 32) r2 = mask[((size_t)(c * 64 + b2)) * 32 + lane];
      }
      if (am) {
        int b3 = __builtin_ctzll(am); am &= am - 1;
        if (lane < 32) r3 = mask[((size_t)(c * 64 + b3)) * 32 + lane];
      }
      supw |= (r0 | r1) | (r2 | r3);
    }
    Mcur = Mnext;
  }

  if (lane < 32) lsup[lane] = supw;
  __syncthreads();
#pragma unroll 4
  for (int k = 0; k < 32; ++k) {
    int e = k * 64 + lane;
    int s = (int)((lsup[k] >> (e & 63)) & 1ull);
    keep[e] = (validv[e] && !s) ? 1 : 0;
  }
}

// ------------------------------------------------ final top-100 + write outputs
__global__ __launch_bounds__(256) void k_finalize(
    const int* __restrict__ keep, const float4* __restrict__ dbox,
    const float* __restrict__ scorev, const int* __restrict__ clsv,
    float* __restrict__ out)
{
  __shared__ short fidx[TOPK_];
  __shared__ char ksh[MCAND];
  const int tid = threadIdx.x;
  for (int e = tid; e < MCAND; e += 256) ksh[e] = (char)keep[e];
  __syncthreads();
  if (tid == 0) {
    int cnt = 0;
    for (int r = 0; r < MCAND && cnt < TOPK_; ++r) if (ksh[r]) fidx[cnt++] = (short)r;
    for (int r = 0; r < MCAND && cnt < TOPK_; ++r) if (!ksh[r]) fidx[cnt++] = (short)r;
  }
  __syncthreads();
  if (tid < TOPK_) {
    int r = fidx[tid];
    float4 b = dbox[r];
    out[tid * 4 + 0] = b.x; out[tid * 4 + 1] = b.y;
    out[tid * 4 + 2] = b.z; out[tid * 4 + 3] = b.w;
    int kp = ksh[r];
    out[400 + tid] = kp ? scorev[r] : -1.0f;
    out[500 + tid] = (float)clsv[r];
    out[600 + tid] = kp ? 1.0f : 0.0f;
  }
}

// ----------------------------------------------------------------------------
extern "C" void kernel_launch(void* const* d_in, const int* in_sizes, int n_in,
                              void* d_out, int out_size, void* d_ws, size_t ws_size,
                              hipStream_t stream) {
  const float* x         = (const float*)d_in[0];
  const float* cls_w     = (const float*)d_in[1];
  const float* cls_b     = (const float*)d_in[2];
  const float* bbox_w    = (const float*)d_in[3];
  const float* bbox_b    = (const float*)d_in[4];
  const float* proposals = (const float*)d_in[5];
  float* out = (float*)d_out;

  char* ws = (char*)d_ws;
  size_t off = 0;
  double* scd   = (double*)(ws + off); off += (size_t)CMAX * 8;
  u32*    cid   = (u32*)(ws + off);    off += (size_t)CMAX * 4;
  double* selS  = (double*)(ws + off); off += (size_t)MCAND * 8;
  u32*    selI  = (u32*)(ws + off);    off += (size_t)MCAND * 4 + 8;
  off = (off + 15) & ~(size_t)15;
  int*    counter = (int*)(ws + off);  off += 16;
  int*    scount  = (int*)(ws + off);  off += 16;
  int*    tbin    = (int*)(ws + off);  off += 16;
  int*    hist    = (int*)(ws + off);  off += (size_t)NBINS * 4;
  int*    cnt     = (int*)(ws + off);  off += (size_t)SURV_MAX * 4;
  double* ssc     = (double*)(ws + off); off += (size_t)SURV_MAX * 8;
  u32*    sid     = (u32*)(ws + off);  off += (size_t)SURV_MAX * 4;
  float4* dbox  = (float4*)(ws + off); off += (size_t)MCAND * 16;
  float4* obox  = (float4*)(ws + off); off += (size_t)MCAND * 16;
  float*  areav = (float*)(ws + off);  off += (size_t)MCAND * 4;
  float*  scorev= (float*)(ws + off);  off += (size_t)MCAND * 4;
  int*    clsv  = (int*)(ws + off);    off += (size_t)MCAND * 4;
  int*    validv= (int*)(ws + off);    off += (size_t)MCAND * 4;
  int*    keep  = (int*)(ws + off);    off += (size_t)MCAND * 4;
  off = (off + 15) & ~(size_t)15;
  u64*    mask  = (u64*)(ws + off);    off += (size_t)MCAND * 32 * 8;

  k_init<<<SURV_MAX / 256, 256, 0, stream>>>(counter, scount, tbin, hist, cnt, selS, selI);
  k_gemm_softmax<<<N_ROWS / 32, 256, 0, stream>>>(x, cls_w, cls_b, scd, cid, counter);
  k_hist<<<64, 256, 0, stream>>>(scd, counter, hist);
  k_thresh<<<1, 256, 0, stream>>>(hist, tbin);
  k_compact<<<64, 256, 0, stream>>>(scd, cid, counter, tbin, ssc, sid, scount);
  k_rank<<<dim3(SURV_MAX / 256, NSPLIT), 256, 0, stream>>>(ssc, sid, scount, cnt);
  k_scatter<<<SURV_MAX / 256, 256, 0, stream>>>(ssc, sid, scount, cnt, selS, selI);
  k_gather_decode<<<MCAND, 256, 0, stream>>>(selS, selI, x, bbox_w, bbox_b, proposals,
                                             dbox, obox, areav, scorev, clsv, validv);
  k_nms_mask<<<MCAND, 256, 0, stream>>>(obox, areav, mask);
  k_nms_reduce<<<1, 64, 0, stream>>>(mask, validv, keep);
  k_finalize<<<1, 256, 0, stream>>>(keep, dbox, scorev, clsv, out);
}

// Round 4
// 498.527 us; speedup vs baseline: 1.3905x; 1.3905x over previous
//
#include <hip/hip_runtime.h>
#include <math.h>

typedef unsigned long long u64;
typedef unsigned int u32;

#define N_ROWS 8192
#define DIM 1024
#define KCLS 80
#define KC1 81
#define MCAND 2048
#define TOPK_ 100
#define CMAX 163840
#define SURV_MAX 32768
#define NSPLIT 4
#define NBINS 8192
#define BIN_BASE 125440
#define SCORE_T 0.05
#define NMS_T 0.5f
#define MAX_COORD_F 1217.0f
#define SCALE_CLAMP_F 4.135166556742356f
#define IMG_W_F 1216.0f
#define IMG_H_F 800.0f

__device__ __forceinline__ int score_bin(double p) {
  u32 bits = __float_as_uint((float)p);
  int b = (int)(bits >> 13) - BIN_BASE;
  return b < 0 ? 0 : (b > NBINS - 1 ? NBINS - 1 : b);
}

__device__ __forceinline__ u64 readlane64(u64 v, int l) {
  u32 lo = __builtin_amdgcn_readlane((u32)v, l);
  u32 hi = __builtin_amdgcn_readlane((u32)(v >> 32), l);
  return ((u64)hi << 32) | (u64)lo;
}

// ---------------------------------------------------------------- init
__global__ void k_init(int* counter, int* scount, int* tbin, int* hist,
                       int* cnt, double* selS, u32* selI) {
  int t = blockIdx.x * blockDim.x + threadIdx.x;
  if (t == 0) { *counter = 0; *scount = 0; *tbin = 0; }
  if (t < NBINS) hist[t] = 0;
  if (t < SURV_MAX) cnt[t] = 0;
  if (t < MCAND) { selS[t] = -1.0; selI[t] = 0u; }  // sentinel (score=-1 -> invalid)
}

// ------------------------------------- cls GEMM (f64 acc) + softmax + compact
#define BK 32
#define XT_STRIDE 34
#define BT_STRIDE 96

__global__ __launch_bounds__(256) void k_gemm_softmax(
    const float* __restrict__ x, const float* __restrict__ w,
    const float* __restrict__ bias, double* __restrict__ scd,
    u32* __restrict__ cid, int* __restrict__ counter)
{
  __shared__ float xt[BK][XT_STRIDE];
  __shared__ float bt[BK][BT_STRIDE];
  __shared__ double red[16][32];
  __shared__ double rowM[32];
  __shared__ double rowS[32];

  const int tid = threadIdx.x;
  const int rb = blockIdx.x * 32;
  const int cx = tid >> 4;   // 0..15
  const int ry = tid & 15;   // 0..15

  double acc[2][6];
#pragma unroll
  for (int i = 0; i < 2; i++)
#pragma unroll
    for (int j = 0; j < 6; j++) acc[i][j] = 0.0;

  const int sr  = tid >> 3;        // 0..31 stage row
  const int skq = (tid & 7) * 4;   // 0,4,...,28

  for (int k0 = 0; k0 < DIM; k0 += BK) {
    float4 xv4 = *(const float4*)(x + (size_t)(rb + sr) * DIM + k0 + skq);
    float breg[12];
#pragma unroll
    for (int q = 0; q < 12; ++q) {
      int e = tid + q * 256;        // 0..3071 over 32x96
      int k = e / 96, c = e - k * 96;
      breg[q] = (c < KC1) ? w[(size_t)(k0 + k) * KC1 + c] : 0.0f;
    }
    __syncthreads();
    xt[skq + 0][sr] = xv4.x; xt[skq + 1][sr] = xv4.y;
    xt[skq + 2][sr] = xv4.z; xt[skq + 3][sr] = xv4.w;
#pragma unroll
    for (int q = 0; q < 12; ++q) ((float*)bt)[tid + q * 256] = breg[q];
    __syncthreads();

#pragma unroll
    for (int k = 0; k < BK; ++k) {
      float2 xv = *(const float2*)&xt[k][ry * 2];
      float2 b0 = *(const float2*)&bt[k][cx * 6];
      float2 b1 = *(const float2*)&bt[k][cx * 6 + 2];
      float2 b2 = *(const float2*)&bt[k][cx * 6 + 4];
      double xd0 = (double)xv.x, xd1 = (double)xv.y;
      double bd[6] = {(double)b0.x, (double)b0.y, (double)b1.x,
                      (double)b1.y, (double)b2.x, (double)b2.y};
#pragma unroll
      for (int j = 0; j < 6; j++) {
        acc[0][j] = fma(xd0, bd[j], acc[0][j]);
        acc[1][j] = fma(xd1, bd[j], acc[1][j]);
      }
    }
    __syncthreads();
  }

  double bb[6];
#pragma unroll
  for (int j = 0; j < 6; j++) {
    int c = cx * 6 + j;
    bb[j] = (c < KC1) ? (double)bias[c] : 0.0;
  }
  double pm[2] = {-1e300, -1e300};
#pragma unroll
  for (int i = 0; i < 2; i++)
#pragma unroll
    for (int j = 0; j < 6; j++) {
      int c = cx * 6 + j;
      if (c < KC1) pm[i] = fmax(pm[i], acc[i][j] + bb[j]);
    }
  red[cx][ry * 2 + 0] = pm[0];
  red[cx][ry * 2 + 1] = pm[1];
  __syncthreads();
  if (tid < 32) {
    double m = -1e300;
#pragma unroll
    for (int q = 0; q < 16; q++) m = fmax(m, red[q][tid]);
    rowM[tid] = m;
  }
  __syncthreads();
  double ps[2] = {0.0, 0.0};
#pragma unroll
  for (int i = 0; i < 2; i++) {
    double m = rowM[ry * 2 + i];
#pragma unroll
    for (int j = 0; j < 6; j++) {
      int c = cx * 6 + j;
      if (c < KC1) ps[i] += exp(acc[i][j] + bb[j] - m);
    }
  }
  __syncthreads();
  red[cx][ry * 2 + 0] = ps[0];
  red[cx][ry * 2 + 1] = ps[1];
  __syncthreads();
  if (tid < 32) {
    double s = 0.0;
#pragma unroll
    for (int q = 0; q < 16; q++) s += red[q][tid];
    rowS[tid] = s;
  }
  __syncthreads();
#pragma unroll
  for (int i = 0; i < 2; i++) {
    int rloc = ry * 2 + i;
    double m = rowM[rloc], s = rowS[rloc];
#pragma unroll
    for (int j = 0; j < 6; j++) {
      int c = cx * 6 + j;
      if (c < KCLS) {
        double p = exp(acc[i][j] + bb[j] - m) / s;
        if (p > SCORE_T) {
          int pos = atomicAdd(counter, 1);
          if (pos < CMAX) {
            scd[pos] = p;
            cid[pos] = (u32)((rb + rloc) * KCLS + c);
          }
        }
      }
    }
  }
}

// -------------------------------------------- histogram of float-key bins
__global__ __launch_bounds__(256) void k_hist(
    const double* __restrict__ sc, const int* __restrict__ counter,
    int* __restrict__ hist)
{
  int C = *counter; if (C > CMAX) C = CMAX;
  for (int e = blockIdx.x * 256 + threadIdx.x; e < C; e += gridDim.x * 256)
    atomicAdd(&hist[score_bin(sc[e])], 1);
}

// -------------------------------------- find threshold bin (suffix >= MCAND)
__global__ __launch_bounds__(256) void k_thresh(
    const int* __restrict__ hist, int* __restrict__ tbin)
{
  __shared__ int h[NBINS];
  __shared__ int segsum[256];
  __shared__ int segsuf[256];
  const int tid = threadIdx.x;
  for (int e = tid; e < NBINS; e += 256) h[e] = hist[e];
  __syncthreads();
  int s = 0;
#pragma unroll
  for (int q = 0; q < NBINS / 256; ++q) s += h[tid * (NBINS / 256) + q];
  segsum[tid] = s;
  __syncthreads();
  if (tid == 0) {
    int run = 0;
    for (int t = 255; t >= 0; --t) { segsuf[t] = run; run += segsum[t]; }
  }
  __syncthreads();
  int run = segsuf[tid];
  if (run < MCAND) {
    const int lo = tid * (NBINS / 256);
    for (int b = lo + NBINS / 256 - 1; b >= lo; --b) {
      run += h[b];
      if (run >= MCAND) { *tbin = b; break; }
    }
  }
}

// ------------------------------------------------- compact survivors (bin>=T)
__global__ __launch_bounds__(256) void k_compact(
    const double* __restrict__ sc, const u32* __restrict__ id,
    const int* __restrict__ counter, const int* __restrict__ tbin,
    double* __restrict__ ssc, u32* __restrict__ sid, int* __restrict__ scount)
{
  int C = *counter; if (C > CMAX) C = CMAX;
  const int T = *tbin;
  for (int e = blockIdx.x * 256 + threadIdx.x; e < C; e += gridDim.x * 256) {
    double p = sc[e];
    if (score_bin(p) >= T) {
      int pos = atomicAdd(scount, 1);
      if (pos < SURV_MAX) { ssc[pos] = p; sid[pos] = id[e]; }
    }
  }
}

// --------------------------- exact rank-count among survivors (j-range split)
__global__ __launch_bounds__(256) void k_rank(
    const double* __restrict__ ssc, const u32* __restrict__ sid,
    const int* __restrict__ scount, int* __restrict__ cnt)
{
  __shared__ double lsc[2048];
  __shared__ u32 lid[2048];
  int S = *scount; if (S > SURV_MAX) S = SURV_MAX;
  const int i = blockIdx.x * 256 + threadIdx.x;
  if (blockIdx.x * 256 >= S) return;
  const double si = (i < S) ? ssc[i] : -2.0;
  const u32 ii = (i < S) ? sid[i] : 0u;
  const int seg = (S + NSPLIT - 1) / NSPLIT;
  const int jlo = blockIdx.y * seg;
  const int jhi = min(S, jlo + seg);
  int c = 0;
  for (int base = jlo; base < jhi; base += 2048) {
    const int n = min(2048, jhi - base);
    __syncthreads();
    for (int e = threadIdx.x; e < n; e += 256) { lsc[e] = ssc[base + e]; lid[e] = sid[base + e]; }
    __syncthreads();
    if (i < S) {
      for (int j = 0; j < n; ++j) {
        double sj = lsc[j];
        c += (sj > si || (sj == si && lid[j] < ii)) ? 1 : 0;
      }
    }
  }
  if (i < S && c > 0) atomicAdd(&cnt[i], c);
}

// ----------------------------------------------------- scatter by final rank
__global__ __launch_bounds__(256) void k_scatter(
    const double* __restrict__ ssc, const u32* __restrict__ sid,
    const int* __restrict__ scount, const int* __restrict__ cnt,
    double* __restrict__ selS, u32* __restrict__ selI)
{
  int S = *scount; if (S > SURV_MAX) S = SURV_MAX;
  const int i = blockIdx.x * 256 + threadIdx.x;
  if (i < S) {
    int c = cnt[i];
    if (c < MCAND) { selS[c] = ssc[i]; selI[c] = sid[i]; }
  }
}

// -------------------------------- per-candidate bbox delta dot + decode + clip
__global__ __launch_bounds__(256) void k_gather_decode(
    const double* __restrict__ selS, const u32* __restrict__ selI,
    const float* __restrict__ x, const float* __restrict__ bw,
    const float* __restrict__ bbias, const float* __restrict__ proposals,
    float4* __restrict__ dbox, float4* __restrict__ obox,
    float* __restrict__ areav, float* __restrict__ scorev,
    int* __restrict__ clsv, int* __restrict__ validv)
{
  __shared__ double wred[4][4];
  const int r = blockIdx.x;
  const double s = selS[r];
  const u32 idx = selI[r];
  const int row = (int)(idx / 80u);
  const int cls = (int)(idx - (u32)row * 80u);

  const float* xr = x + (size_t)row * DIM;
  const float4* bwv = (const float4*)bw;  // [DIM][80] of float4
  double a0 = 0, a1 = 0, a2 = 0, a3 = 0;
  for (int k = threadIdx.x; k < DIM; k += 256) {
    double xv = (double)xr[k];
    float4 wv = bwv[(size_t)k * 80 + cls];
    a0 = fma(xv, (double)wv.x, a0);
    a1 = fma(xv, (double)wv.y, a1);
    a2 = fma(xv, (double)wv.z, a2);
    a3 = fma(xv, (double)wv.w, a3);
  }
#pragma unroll
  for (int off = 32; off > 0; off >>= 1) {
    a0 += __shfl_down(a0, off);
    a1 += __shfl_down(a1, off);
    a2 += __shfl_down(a2, off);
    a3 += __shfl_down(a3, off);
  }
  int lane = threadIdx.x & 63, wid = threadIdx.x >> 6;
  if (lane == 0) { wred[wid][0] = a0; wred[wid][1] = a1; wred[wid][2] = a2; wred[wid][3] = a3; }
  __syncthreads();
  if (threadIdx.x == 0) {
    double d0 = wred[0][0] + wred[1][0] + wred[2][0] + wred[3][0] + (double)bbias[cls * 4 + 0];
    double d1 = wred[0][1] + wred[1][1] + wred[2][1] + wred[3][1] + (double)bbias[cls * 4 + 1];
    double d2 = wred[0][2] + wred[1][2] + wred[2][2] + wred[3][2] + (double)bbias[cls * 4 + 2];
    double d3 = wred[0][3] + wred[1][3] + wred[2][3] + wred[3][3] + (double)bbias[cls * 4 + 3];
    float4 p = ((const float4*)proposals)[row];
    float w = p.z - p.x, h = p.w - p.y;
    float cxx = p.x + 0.5f * w, cyy = p.y + 0.5f * h;
    float dx = (float)d0 / 10.0f;
    float dy = (float)d1 / 10.0f;
    float dw = fminf((float)d2 / 5.0f, SCALE_CLAMP_F);
    float dh = fminf((float)d3 / 5.0f, SCALE_CLAMP_F);
    float pcx = dx * w + cxx, pcy = dy * h + cyy;
    float pw = expf(dw) * w, ph = expf(dh) * h;
    float x1 = pcx - 0.5f * pw, y1 = pcy - 0.5f * ph;
    float x2 = pcx + 0.5f * pw, y2 = pcy + 0.5f * ph;
    x1 = fminf(fmaxf(x1, 0.0f), IMG_W_F);
    x2 = fminf(fmaxf(x2, 0.0f), IMG_W_F);
    y1 = fminf(fmaxf(y1, 0.0f), IMG_H_F);
    y2 = fminf(fmaxf(y2, 0.0f), IMG_H_F);
    float4 db = {x1, y1, x2, y2};
    dbox[r] = db;
    float ofs = (float)cls * MAX_COORD_F;
    float4 ob = {x1 + ofs, y1 + ofs, x2 + ofs, y2 + ofs};
    obox[r] = ob;
    areav[r] = (ob.z - ob.x) * (ob.w - ob.y);
    scorev[r] = (float)s;
    clsv[r] = cls;
    validv[r] = (s > SCORE_T) ? 1 : 0;
  }
}

// ------------------------------------------------ pairwise suppression bitmask
__global__ __launch_bounds__(256) void k_nms_mask(
    const float4* __restrict__ obox, const float* __restrict__ areav,
    u64* __restrict__ mask)
{
  __shared__ float4 sb[MCAND];
  __shared__ float sa[MCAND];
  const int i = blockIdx.x;
  for (int e = threadIdx.x; e < MCAND; e += 256) { sb[e] = obox[e]; sa[e] = areav[e]; }
  __syncthreads();
  float4 bi = sb[i];
  float ai = sa[i];
  int lane = threadIdx.x & 63, wid = threadIdx.x >> 6;
#pragma unroll
  for (int it = 0; it < MCAND / 256; ++it) {
    int j = it * 256 + threadIdx.x;
    float4 bj = sb[j];
    float xx1 = fmaxf(bi.x, bj.x);
    float yy1 = fmaxf(bi.y, bj.y);
    float xx2 = fminf(bi.z, bj.z);
    float yy2 = fminf(bi.w, bj.w);
    float inter = fmaxf(xx2 - xx1, 0.0f) * fmaxf(yy2 - yy1, 0.0f);
    float uni = ai + sa[j] - inter;
    float iou = inter / fmaxf(uni, 1e-9f);
    bool pred = (iou > NMS_T) && (j > i);
    u64 b = __ballot(pred);
    if (lane == 0) mask[(size_t)i * 32 + it * 4 + wid] = b;
  }
}

// ---- sequential suppression scan: wave0 resolves from LDS, waves 1-3 stage
#define GCH 2   // chunks (of 64 candidates) per staged group
__global__ __launch_bounds__(256) void k_nms_reduce(
    const u64* __restrict__ mask, const int* __restrict__ validv,
    int* __restrict__ keep)
{
  __shared__ u64 buf[2][GCH * 64 * 32];   // 2 x 32 KB double buffer
  const int tid = threadIdx.x;
  const int lane = tid & 63;
  const int wv = tid >> 6;

  // prologue: all threads stage group 0
  for (int e = tid; e < GCH * 64 * 32; e += 256) buf[0][e] = mask[e];

  // wave 0 builds validw: lane w (w<32) holds valid word w
  u64 validw = 0, supw = 0;
  if (wv == 0) {
    for (int k = 0; k < 32; ++k) {
      u64 b = __ballot(validv[k * 64 + lane] != 0);
      if (lane == k) validw = b;
    }
  }
  __syncthreads();

  for (int g = 0; g < 32 / GCH; ++g) {
    const int pb = g & 1;
    if (wv != 0) {
      if (g + 1 < 32 / GCH) {           // stage next group into other buffer
        const u64* src = mask + (size_t)(g + 1) * (GCH * 64 * 32);
        for (int e = tid - 64; e < GCH * 64 * 32; e += 192)
          buf[pb ^ 1][e] = src[e];
      }
    } else {
      for (int lc = 0; lc < GCH; ++lc) {
        const int c = g * GCH + lc;
        // diagonal word of each row of this chunk (row c*64+lane, word c)
        u64 d = buf[pb][(lc * 64 + lane) * 32 + c];
        u64 s_sup = readlane64(supw, c);
        u64 s_val = readlane64(validw, c);
        u64 todo = s_val & ~s_sup;
        u64 aliveM = 0;
        while (todo) {
          int b = __builtin_ctzll(todo);
          b = __builtin_amdgcn_readfirstlane(b);
          u64 row = readlane64(d, b);
          s_sup |= row;
          aliveM |= (1ull << b);
          u64 done = (b == 63) ? ~0ull : ((1ull << (b + 1)) - 1);
          todo = s_val & ~s_sup & ~done;
        }
        // apply all alive rows of this chunk (branch-free, both wave halves)
        const int w = lane & 31;
        const int hb = lane >> 5;       // half 0: b=0..31, half 1: b=32..63
        u64 partial = 0;
#pragma unroll
        for (int q = 0; q < 32; ++q) {
          int b = hb * 32 + q;
          u64 sel = (u64)0 - ((aliveM >> b) & 1ull);
          partial |= buf[pb][(lc * 64 + b) * 32 + w] & sel;
        }
        u64 other = (u64)__shfl_xor((long long)partial, 32);
        if (lane < 32) supw |= partial | other;
      }
    }
    __syncthreads();
  }

  if (wv == 0) {
    for (int k = 0; k < 32; ++k) {
      u64 s = readlane64(supw, k);
      int e = k * 64 + lane;
      int sb = (int)((s >> lane) & 1ull);
      keep[e] = (validv[e] && !sb) ? 1 : 0;
    }
  }
}

// ------------------------------------------------ final top-100 + write outputs
__global__ __launch_bounds__(256) void k_finalize(
    const int* __restrict__ keep, const float4* __restrict__ dbox,
    const float* __restrict__ scorev, const int* __restrict__ clsv,
    float* __restrict__ out)
{
  __shared__ short fidx[TOPK_];
  __shared__ char ksh[MCAND];
  const int tid = threadIdx.x;
  for (int e = tid; e < MCAND; e += 256) ksh[e] = (char)keep[e];
  __syncthreads();
  if (tid == 0) {
    int cnt = 0;
    for (int r = 0; r < MCAND && cnt < TOPK_; ++r) if (ksh[r]) fidx[cnt++] = (short)r;
    for (int r = 0; r < MCAND && cnt < TOPK_; ++r) if (!ksh[r]) fidx[cnt++] = (short)r;
  }
  __syncthreads();
  if (tid < TOPK_) {
    int r = fidx[tid];
    float4 b = dbox[r];
    out[tid * 4 + 0] = b.x; out[tid * 4 + 1] = b.y;
    out[tid * 4 + 2] = b.z; out[tid * 4 + 3] = b.w;
    int kp = ksh[r];
    out[400 + tid] = kp ? scorev[r] : -1.0f;
    out[500 + tid] = (float)clsv[r];
    out[600 + tid] = kp ? 1.0f : 0.0f;
  }
}

// ----------------------------------------------------------------------------
extern "C" void kernel_launch(void* const* d_in, const int* in_sizes, int n_in,
                              void* d_out, int out_size, void* d_ws, size_t ws_size,
                              hipStream_t stream) {
  const float* x         = (const float*)d_in[0];
  const float* cls_w     = (const float*)d_in[1];
  const float* cls_b     = (const float*)d_in[2];
  const float* bbox_w    = (const float*)d_in[3];
  const float* bbox_b    = (const float*)d_in[4];
  const float* proposals = (const float*)d_in[5];
  float* out = (float*)d_out;

  char* ws = (char*)d_ws;
  size_t off = 0;
  double* scd   = (double*)(ws + off); off += (size_t)CMAX * 8;
  u32*    cid   = (u32*)(ws + off);    off += (size_t)CMAX * 4;
  double* selS  = (double*)(ws + off); off += (size_t)MCAND * 8;
  u32*    selI  = (u32*)(ws + off);    off += (size_t)MCAND * 4 + 8;
  off = (off + 15) & ~(size_t)15;
  int*    counter = (int*)(ws + off);  off += 16;
  int*    scount  = (int*)(ws + off);  off += 16;
  int*    tbin    = (int*)(ws + off);  off += 16;
  int*    hist    = (int*)(ws + off);  off += (size_t)NBINS * 4;
  int*    cnt     = (int*)(ws + off);  off += (size_t)SURV_MAX * 4;
  double* ssc     = (double*)(ws + off); off += (size_t)SURV_MAX * 8;
  u32*    sid     = (u32*)(ws + off);  off += (size_t)SURV_MAX * 4;
  float4* dbox  = (float4*)(ws + off); off += (size_t)MCAND * 16;
  float4* obox  = (float4*)(ws + off); off += (size_t)MCAND * 16;
  float*  areav = (float*)(ws + off);  off += (size_t)MCAND * 4;
  float*  scorev= (float*)(ws + off);  off += (size_t)MCAND * 4;
  int*    clsv  = (int*)(ws + off);    off += (size_t)MCAND * 4;
  int*    validv= (int*)(ws + off);    off += (size_t)MCAND * 4;
  int*    keep  = (int*)(ws + off);    off += (size_t)MCAND * 4;
  off = (off + 15) & ~(size_t)15;
  u64*    mask  = (u64*)(ws + off);    off += (size_t)MCAND * 32 * 8;

  k_init<<<SURV_MAX / 256, 256, 0, stream>>>(counter, scount, tbin, hist, cnt, selS, selI);
  k_gemm_softmax<<<N_ROWS / 32, 256, 0, stream>>>(x, cls_w, cls_b, scd, cid, counter);
  k_hist<<<64, 256, 0, stream>>>(scd, counter, hist);
  k_thresh<<<1, 256, 0, stream>>>(hist, tbin);
  k_compact<<<64, 256, 0, stream>>>(scd, cid, counter, tbin, ssc, sid, scount);
  k_rank<<<dim3(SURV_MAX / 256, NSPLIT), 256, 0, stream>>>(ssc, sid, scount, cnt);
  k_scatter<<<SURV_MAX / 256, 256, 0, stream>>>(ssc, sid, scount, cnt, selS, selI);
  k_gather_decode<<<MCAND, 256, 0, stream>>>(selS, selI, x, bbox_w, bbox_b, proposals,
                                             dbox, obox, areav, scorev, clsv, validv);
  k_nms_mask<<<MCAND, 256, 0, stream>>>(obox, areav, mask);
  k_nms_reduce<<<1, 256, 0, stream>>>(mask, validv, keep);
  k_finalize<<<1, 256, 0, stream>>>(keep, dbox, scorev, clsv, out);
}